// Round 18
// baseline (521.997 us; speedup 1.0000x reference)
//
#include <hip/hip_runtime.h>
#include <hip/hip_fp16.h>
#include <math.h>

// Problem constants
#define BN 4
#define CC 31
#define HH 512
#define WW 512
#define HWSZ 262144  // 512*512

// Workspace: z2 field (b,c,h,w) fp16, then float stats region.
static const size_t Z2F = (size_t)BN * CC * HWSZ;
#define T_OFF   0
#define SSQ_OFF 124
#define R0_OFF  248
#define RL_OFF  372
#define C0_OFF  496
#define CL_OFF  620
#define COR_OFF 744

typedef short v8s __attribute__((ext_vector_type(8)));      // 8 bf16/f16 bits
typedef _Float16 v8h __attribute__((ext_vector_type(8)));   // 8 f16
typedef float v4f __attribute__((ext_vector_type(4)));      // 4 f32 (C/D frag)
typedef _Float16 v4h __attribute__((ext_vector_type(4)));   // 4 f16 (K=16 frag)

__device__ __forceinline__ short f2bf(float f) {   // f32 -> bf16 (RNE)
    unsigned u = __float_as_uint(f);
    return (short)((u + 0x7FFFu + ((u >> 16) & 1u)) >> 16);
}

// gelu(s) with Abramowitz-Stegun 7.1.26 erf (max abs err 1.5e-7 -- far below
// fp16 quantum). Straight-line: rcp + 5 FMA + v_exp, no branches.
__device__ __forceinline__ float fast_gelu(float s) {
    const float a  = fabsf(s) * 0.70710678118654752f;
    const float t  = __builtin_amdgcn_rcpf(1.f + 0.3275911f * a);
    float p = 1.061405429f;
    p = p * t - 1.453152027f;
    p = p * t + 1.421413741f;
    p = p * t - 0.284496736f;
    p = p * t + 0.254829592f;
    const float e  = __expf(-a * a);
    const float er = copysignf(1.f - p * t * e, s);
    return 0.5f * s * (1.f + er);
}

// XCD-aware swizzle: each XCD gets a contiguous 512-tile region.
__device__ __forceinline__ void swizzle_tile(int& b, int& ty0, int& tx0) {
    const int lid = blockIdx.x + 32 * blockIdx.y + 1024 * blockIdx.z;
    const int vid = ((lid & 7) << 9) + (lid >> 3);
    b = vid >> 10;
    const int rem = vid & 1023;
    ty0 = (rem >> 5) << 4;
    tx0 = (rem & 31) << 4;
}

// ---------------------------------------------------------------------------
// Kernel A: 16x16 tile. Zb aliased on Ff; grid-limited 4 blocks/CU. NEW:
// LN phase issues BOTH pixels' loads up-front (threads 0-67 own 2 pixels;
// previously their 2nd pixel's 31 loads waited behind the 1st pixel's
// compute -- one extra serialized ~900cy HBM wait on the phase critical
// path). 62 f32 + temps ~= 105 VGPR, under the 128 cap at (256,4).
// ---------------------------------------------------------------------------
__global__ __launch_bounds__(256, 4) void blockNL_k_stage1(
    const float* __restrict__ z,
    const float* __restrict__ nz_w, const float* __restrict__ nz_b,
    const float* __restrict__ t1w, const float* __restrict__ t1b,
    const float* __restrict__ t2w, const float* __restrict__ t2b,
    const float* __restrict__ g1w, const float* __restrict__ g1b,
    const float* __restrict__ g2w, const float* __restrict__ g2b,
    __half* __restrict__ z2out, float* __restrict__ stats)
{
    __shared__ __align__(16) short Vb[324 * 32];   // LN halo, bf16 [px][32ch] 20736 B
    __shared__ __align__(16) short Wp[16 * 32];    // per-pass 1x1 W bf16      1024 B
    __shared__ __align__(16) union {
        short Ff[324 * 16];                        // per-pass field f16      10368 B
        short Zb[16 * 264];                        // per-pass z1 f16 stats    8448 B
    } uf;
    __shared__ __align__(16) short Wd[10 * 16];    // per-pass dw3 W+bias f16   320 B

    const int tid = threadIdx.x;
    int b, ty0, tx0;
    swizzle_tile(b, ty0, tx0);

    const int w = tid >> 6, lane = tid & 63, quad = lane >> 4, m15 = lane & 15;
    const int ty = tid >> 4, tx = tid & 15;
    const int gy = ty0 + ty, gx = tx0 + tx;

    // LN normalize+pack from loaded regs (v mutated), store to Vb[hp]
    auto ln_pack = [&](float* v, int hp) {
        float mu = 0.f;
        #pragma unroll
        for (int c = 0; c < CC; ++c) mu += v[c];
        mu *= (1.f / 31.f);
        float var = 0.f;
        #pragma unroll
        for (int c = 0; c < CC; ++c) { float d = v[c] - mu; v[c] = d; var += d * d; }
        var *= (1.f / 31.f);
        const float rs = rsqrtf(var + 1e-5f);
        #pragma unroll
        for (int c = 0; c < CC; ++c) v[c] = v[c] * rs * nz_w[c] + nz_b[c];
        int pk[16];
        #pragma unroll
        for (int i = 0; i < 15; ++i)
            asm("v_cvt_pk_bf16_f32 %0, %1, %2"
                : "=v"(pk[i]) : "v"(v[2 * i]), "v"(v[2 * i + 1]));
        asm("v_cvt_pk_bf16_f32 %0, %1, %2"
            : "=v"(pk[15]) : "v"(v[30]), "v"(0.f));
        int* dst = (int*)&Vb[hp * 32];
        #pragma unroll
        for (int q = 0; q < 4; ++q) {
            int4 t; t.x = pk[q*4]; t.y = pk[q*4+1]; t.z = pk[q*4+2]; t.w = pk[q*4+3];
            ((int4*)dst)[q] = t;
        }
    };
    auto zero_pack = [&](int hp) {
        int4 t; t.x = 0; t.y = 0; t.z = 0; t.w = 0;
        int* dst = (int*)&Vb[hp * 32];
        #pragma unroll
        for (int q = 0; q < 4; ++q) ((int4*)dst)[q] = t;
    };

    // ---- phase 1: stage LN field (bf16) into Vb; both pixels' loads first --
    {
        const int hp1 = tid;
        const int hy1 = hp1 / 18, hx1 = hp1 - hy1 * 18;
        const int zy1 = ty0 + hy1 - 1, zx1 = tx0 + hx1 - 1;
        const bool val1 = ((unsigned)zy1 < (unsigned)HH) && ((unsigned)zx1 < (unsigned)WW);
        const bool has2 = (tid < 68);
        const int hp2 = tid + 256;
        const int hy2 = hp2 / 18, hx2 = hp2 - hy2 * 18;
        const int zy2 = ty0 + hy2 - 1, zx2 = tx0 + hx2 - 1;
        const bool val2 = has2 && ((unsigned)zy2 < (unsigned)HH) &&
                          ((unsigned)zx2 < (unsigned)WW);
        float v1[CC], v2[CC];
        if (val1) {
            const float* zp = z + (size_t)b * CC * HWSZ + (size_t)zy1 * WW + zx1;
            #pragma unroll
            for (int c = 0; c < CC; ++c) v1[c] = zp[(size_t)c * HWSZ];
        }
        if (val2) {
            const float* zp = z + (size_t)b * CC * HWSZ + (size_t)zy2 * WW + zx2;
            #pragma unroll
            for (int c = 0; c < CC; ++c) v2[c] = zp[(size_t)c * HWSZ];
        }
        if (val1) ln_pack(v1, hp1); else zero_pack(hp1);
        if (has2) { if (val2) ln_pack(v2, hp2); else zero_pack(hp2); }
    }

    // per-pass 1x1 weight tile: rows ct*16..ct*16+15 of t1w (p<2) or g1w
    auto wbuild = [&](int p) {
        const float* W1 = (p >= 2) ? g1w : t1w;
        const int ct = p & 1;
        const int m = tid >> 4, kp = tid & 15;
        const int gr = ct * 16 + m;
        const int k0 = 2 * kp, k1 = k0 + 1;
        float w0 = 0.f, w1 = 0.f;
        if (gr < CC) {
            if (k0 < CC) w0 = W1[gr * CC + k0];
            if (k1 < CC) w1 = W1[gr * CC + k1];
        }
        ((int*)Wp)[m * 16 + kp] =
            (int)((unsigned short)f2bf(w0) | ((unsigned)(unsigned short)f2bf(w1) << 16));
    };

    // per-pass dw3 weight/bias table (fp16): rows 0-8 = taps, row 9 = bias
    auto wdbuild = [&](int p) {
        if (tid < 160) {
            const float* W3 = (p >= 2) ? g2w : t2w;
            const float* B3 = (p >= 2) ? g2b : t2b;
            const int tap = tid >> 4, r = tid & 15;
            const int ch = (p & 1) * 16 + r;
            float v = 0.f;
            if (ch < CC) v = (tap < 9) ? W3[ch * 9 + tap] : B3[ch];
            Wd[tap * 16 + r] = (short)__half_as_ushort(__float2half(v));
        }
    };

    // MFMA matvec: field[px][16] f16; half-index XOR swizzle keyed on px bit 2
    auto mfma_pass = [&](int p) {
        const int ct = p & 1;
        const float* B1 = (p >= 2) ? g1b : t1b;
        const v8s afrag = *(const v8s*)&Wp[m15 * 32 + quad * 8];
        float bias[4];
        #pragma unroll
        for (int r = 0; r < 4; ++r) {
            const int row = ct * 16 + quad * 4 + r;
            bias[r] = (row < CC) ? B1[row] : 0.f;
        }
        for (int j = w; j < 21; j += 4) {
            const int px = j * 16 + m15;
            const int pc = (px < 324) ? px : 323;   // clamp tail (garbage, unstored)
            const v8s bfrag = *(const v8s*)&Vb[pc * 32 + quad * 8];
            v4f acc = {0.f, 0.f, 0.f, 0.f};
            acc = __builtin_amdgcn_mfma_f32_16x16x32_bf16(afrag, bfrag, acc, 0, 0, 0);
            if (px < 324) {
                unsigned d0 = (unsigned)__half_as_ushort(__float2half(acc[0] + bias[0]))
                            | ((unsigned)__half_as_ushort(__float2half(acc[1] + bias[1])) << 16);
                unsigned d1 = (unsigned)__half_as_ushort(__float2half(acc[2] + bias[2]))
                            | ((unsigned)__half_as_ushort(__float2half(acc[3] + bias[3])) << 16);
                const int half = (quad >> 1) ^ ((px >> 2) & 1);
                int2 st; st.x = (int)d0; st.y = (int)d1;
                *(int2*)&uf.Ff[px * 16 + half * 8 + (quad & 1) * 4] = st;
            }
        }
    };

    // dw3 compute (packed fp16): accv[i] = half2 of channels (2i, 2i+1)
    auto dw3_compute = [&](__half2* accv) {
        {
            const v8s b0 = *(const v8s*)&Wd[9 * 16 + 0];
            const v8s b1 = *(const v8s*)&Wd[9 * 16 + 8];
            #pragma unroll
            for (int i = 0; i < 4; ++i) {
                accv[i]     = ((const __half2*)&b0)[i];
                accv[4 + i] = ((const __half2*)&b1)[i];
            }
        }
        #pragma unroll
        for (int dy = 0; dy < 3; ++dy)
            #pragma unroll
            for (int dx = 0; dx < 3; ++dx) {
                const int tap = dy * 3 + dx;
                const int hp = (ty + dy) * 18 + (tx + dx);
                const int sel = (hp >> 2) & 1;
                const v8s f0 = *(const v8s*)&uf.Ff[hp * 16 + sel * 8];        // ch 0-7
                const v8s f1 = *(const v8s*)&uf.Ff[hp * 16 + (sel ^ 1) * 8];  // ch 8-15
                const v8s w0 = *(const v8s*)&Wd[tap * 16 + 0];
                const v8s w1 = *(const v8s*)&Wd[tap * 16 + 8];
                #pragma unroll
                for (int i = 0; i < 4; ++i) {
                    accv[i]     = __hfma2(((const __half2*)&w0)[i],
                                          ((const __half2*)&f0)[i], accv[i]);
                    accv[4 + i] = __hfma2(((const __half2*)&w1)[i],
                                          ((const __half2*)&f1)[i], accv[4 + i]);
                }
            }
    };

    // T-pass write half: Zb (aliased on Ff -- caller barriers first) + edges
    auto dw3_writeT = [&](int ct, const __half2* accv) {
        #pragma unroll
        for (int i = 0; i < 8; ++i) {
            const unsigned u = *(const unsigned*)&accv[i];
            uf.Zb[(2 * i) * 264 + tid]     = (short)(u & 0xFFFFu);
            uf.Zb[(2 * i + 1) * 264 + tid] = (short)(u >> 16);
        }
        const bool top = (gy == 0), bot = (gy == HH - 1);
        const bool lef = (gx == 0), rig = (gx == WW - 1);
        if (top | bot | lef | rig) {
            #pragma unroll
            for (int r = 0; r < 16; ++r) {
                const int ch = ct * 16 + r;
                if (ch < CC) {
                    const unsigned u = *(const unsigned*)&accv[r >> 1];
                    const float sT = __half2float(__ushort_as_half(
                        (unsigned short)((r & 1) ? (u >> 16) : (u & 0xFFFFu))));
                    if (top) atomicAdd(&stats[R0_OFF + b * CC + ch], sT);
                    if (bot) atomicAdd(&stats[RL_OFF + b * CC + ch], sT);
                    if (lef) atomicAdd(&stats[C0_OFF + b * CC + ch], sT);
                    if (rig) atomicAdd(&stats[CL_OFF + b * CC + ch], sT);
                    if ((top || bot) && (lef || rig))
                        stats[COR_OFF + (b * CC + ch) * 4 +
                              (bot ? 2 : 0) + (rig ? 1 : 0)] = sT;
                }
            }
        }
    };

    // G-pass write half: z2 field to global (no LDS writes)
    auto dw3_writeG = [&](int ct, const __half2* accv) {
        const size_t zbase = (size_t)b * CC * HWSZ + (size_t)gy * WW + gx;
        #pragma unroll
        for (int i = 0; i < 8; ++i) {
            const unsigned u = *(const unsigned*)&accv[i];
            const int ch0 = ct * 16 + 2 * i, ch1 = ch0 + 1;
            z2out[zbase + (size_t)ch0 * HWSZ] =
                __ushort_as_half((unsigned short)(u & 0xFFFFu));
            if (ch1 < CC)
                z2out[zbase + (size_t)ch1 * HWSZ] =
                    __ushort_as_half((unsigned short)(u >> 16));
        }
    };

    // stats: waves 0,1 = sums (ks halves), waves 2,3 = ssq (ks halves); f16
    auto stats_pass = [&](int ct) {
        const bool dosq = (w >> 1);
        const int kh = w & 1;
        v8h onesh;
        #pragma unroll
        for (int i = 0; i < 8; ++i) onesh[i] = (_Float16)1.f;
        v4f acc = {0.f, 0.f, 0.f, 0.f};
        #pragma unroll
        for (int i = 0; i < 4; ++i) {
            const int ks = kh * 4 + i;
            const v8h bf = *(const v8h*)&uf.Zb[m15 * 264 + ks * 32 + quad * 8];
            acc = __builtin_amdgcn_mfma_f32_16x16x32_f16(dosq ? bf : onesh, bf, acc, 0, 0, 0);
        }
        if (!dosq) {
            if (quad == 0) {
                const int ch = ct * 16 + m15;
                if (ch < CC) atomicAdd(&stats[T_OFF + b * CC + ch], acc[0]);
            }
        } else {
            if ((m15 >> 2) == quad) {   // diagonal lane for n = m15
                const int r = m15 & 3;
                const int ch = ct * 16 + m15;
                if (ch < CC) atomicAdd(&stats[SSQ_OFF + b * CC + ch], acc[r]);
            }
        }
    };

    __half2 accv[8];

    wbuild(0); wdbuild(0);
    __syncthreads();
    mfma_pass(0);
    __syncthreads();
    dw3_compute(accv);           // reads Ff(0)
    __syncthreads();             // all reads done -> safe to alias-write
    dw3_writeT(0, accv);
    __syncthreads();
    stats_pass(0); wbuild(1); wdbuild(1);
    __syncthreads();
    mfma_pass(1);                // rewrites Ff (clobbers Zb(0) -- consumed)
    __syncthreads();
    dw3_compute(accv);
    __syncthreads();
    dw3_writeT(1, accv);
    __syncthreads();
    stats_pass(1); wbuild(2); wdbuild(2);
    __syncthreads();
    mfma_pass(2);
    __syncthreads();
    dw3_compute(accv); dw3_writeG(2, accv); wbuild(3);
    __syncthreads();
    mfma_pass(3); wdbuild(3);
    __syncthreads();
    dw3_compute(accv); dw3_writeG(3, accv);
}

// ---------------------------------------------------------------------------
// Kernel C: channel-pair-packed fp16 data plane + fused attention prologue +
// in-loop T14 staging split (round-17 winner, unchanged).
// LDS: 11584(uu) + 10240(Ub) + 5120(A2) + 1152(W) + 128(vb2s) = 28224 B.
// ---------------------------------------------------------------------------
__global__ __launch_bounds__(256, 4) void blockNL_k_out(
    const float* __restrict__ x, const float* __restrict__ z,
    const float* __restrict__ nx_b,
    const float* __restrict__ p1w, const float* __restrict__ p1b,
    const float* __restrict__ p2w, const float* __restrict__ p2b,
    const float* __restrict__ ww,  const float* __restrict__ wb,
    const float* __restrict__ vw,  const float* __restrict__ vb,
    const float* __restrict__ pe1w, const float* __restrict__ pe2w,
    const __half* __restrict__ z2, const float* __restrict__ stats,
    float* __restrict__ out)
{
    __shared__ __align__(16) union {
        struct {
            unsigned zb2[4][400];                   // half2 [pair][20x20 px]
            unsigned qb2[4][324];                   // half2 [pair][18x18 px]
        } s;
        struct {
            float x1v[CC][9];
            float dxs[CC];
            float att[CC][CC];
            float WA[CC][CC];
        } a;
    } uu;
    __shared__ __align__(16) short Ub[256 * 20];    // per-chunk U [px][16+pad] f16
    __shared__ __align__(16) short A2[4 * 32 * 20]; // per-chunk A [ci][e][16+pad] f16
    __shared__ unsigned W1h[144];                   // pe1w half2 [ci][tap][pair]
    __shared__ unsigned W2h[144];                   // pe2w half2 [ci][tap][pair]
    __shared__ float vb2s[32];                      // folded v-bias

    const int tid = threadIdx.x;
    int b, ty0, tx0;
    swizzle_tile(b, ty0, tx0);
    const int ty = tid >> 4, tx = tid & 15;
    const int gy = ty0 + ty, gx = tx0 + tx;

    // ---- fused attention prologue, phase 1: x1v/dxs, vb2, A2 init, W tables
    {
        const float cnt[9] = {1.f, 510.f, 1.f, 510.f, 260100.f, 510.f, 1.f, 510.f, 1.f};
        if (tid < CC) {
            const float a = nx_b[0];
            const float u = p1w[tid] * a + p1b[tid];
            float w9[9];
            #pragma unroll
            for (int k = 0; k < 9; ++k) w9[k] = p2w[tid * 9 + k];
            float ssq = 0.f;
            #pragma unroll
            for (int ry = 0; ry < 3; ++ry) {
                #pragma unroll
                for (int rx = 0; rx < 3; ++rx) {
                    float wsum = 0.f;
                    #pragma unroll
                    for (int ky = 0; ky < 3; ++ky) {
                        #pragma unroll
                        for (int kx = 0; kx < 3; ++kx) {
                            const bool okr = (ry == 1) || (ry == 0 && ky >= 1) || (ry == 2 && ky <= 1);
                            const bool okc = (rx == 1) || (rx == 0 && kx >= 1) || (rx == 2 && kx <= 1);
                            if (okr && okc) wsum += w9[ky * 3 + kx];
                        }
                    }
                    const float val = u * wsum + p2b[tid];
                    uu.a.x1v[tid][ry * 3 + rx] = val;
                    ssq += cnt[ry * 3 + rx] * val * val;
                }
            }
            uu.a.dxs[tid] = fmaxf(sqrtf(ssq), 1e-12f);
        }
        if (tid >= 64 && tid < 96) {
            const int e = tid - 64;
            float s = vb[e];
            #pragma unroll
            for (int c = 0; c < CC; ++c) s += vw[e * 32 + c + 1] * wb[c];
            vb2s[e] = s;
        }
    }
    // A2 init: k<8 -> vw[e][ci*8+k]; k>=8 -> 0 (M2 overwrites d<31 slots later)
    for (int idx = tid; idx < 2048; idx += 256) {
        const int ci = idx >> 9, e = (idx >> 4) & 31, k = idx & 15;
        const int ch = ci * 8 + (k & 7);
        float v = 0.f;
        if (k < 8 && ch < 31) v = vw[e * 32 + 1 + ch];
        A2[(ci * 32 + e) * 20 + k] = (short)__half_as_ushort(__float2half(v));
    }
    // weight tables: [ci*36 + tap*4 + pair] = half2(w[ch0], w[ch1])
    for (int idx = tid; idx < 288; idx += 256) {
        const int t = (idx >= 144);
        const int r = idx - t * 144;
        const int ci = r / 36, rem = r - ci * 36;
        const int tap = rem >> 2, pr = rem & 3;
        const int ch0 = ci * 8 + 2 * pr, ch1 = ch0 + 1;
        const float* Ws = t ? pe2w : pe1w;
        const float a = Ws[ch0 * 9 + tap];                    // ch0 <= 30
        const float bb = (ch1 < 31) ? Ws[ch1 * 9 + tap] : 0.f;
        const unsigned u = (unsigned)__half_as_ushort(__float2half(a))
                         | ((unsigned)__half_as_ushort(__float2half(bb)) << 16);
        (t ? W2h : W1h)[r] = u;
    }
    __syncthreads();
    // ---- phase 2: att rows (thread c owns row c; softmax in f32) ----
    if (tid < CC) {
        const int c = tid;
        const float Tt  = stats[T_OFF  + b * CC + c];
        const float sq  = stats[SSQ_OFF + b * CC + c];
        const float r0  = stats[R0_OFF + b * CC + c];
        const float rL  = stats[RL_OFF + b * CC + c];
        const float c0  = stats[C0_OFF + b * CC + c];
        const float cL  = stats[CL_OFF + b * CC + c];
        const float k00 = stats[COR_OFF + (b * CC + c) * 4 + 0];
        const float k01 = stats[COR_OFF + (b * CC + c) * 4 + 1];
        const float k10 = stats[COR_OFF + (b * CC + c) * 4 + 2];
        const float k11 = stats[COR_OFF + (b * CC + c) * 4 + 3];
        float T[9];
        T[0] = k00; T[2] = k01; T[6] = k10; T[8] = k11;
        T[1] = r0 - k00 - k01;
        T[7] = rL - k10 - k11;
        T[3] = c0 - k00 - k10;
        T[5] = cL - k01 - k11;
        T[4] = Tt - r0 - rL - c0 - cL + k00 + k01 + k10 + k11;
        const float dz = fmaxf(sqrtf(sq), 1e-12f);

        float Arow[CC];
        float mx = -3.4e38f;
        #pragma unroll
        for (int d = 0; d < CC; ++d) {
            float s = 0.f;
            #pragma unroll
            for (int r = 0; r < 9; ++r) s += T[r] * uu.a.x1v[d][r];
            s = s / (dz * uu.a.dxs[d]);
            Arow[d] = s;
            mx = fmaxf(mx, s);
        }
        float den = 0.f;
        #pragma unroll
        for (int d = 0; d < CC; ++d) { float e = __expf(Arow[d] - mx); Arow[d] = e; den += e; }
        const float inv = 1.f / den;
        #pragma unroll
        for (int d = 0; d < CC; ++d) uu.a.att[c][d] = Arow[d] * inv;
    }
    __syncthreads();
    // ---- phase 3: WA = ww * att  (961 dots over 256 threads) ----
    for (int idx = tid; idx < CC * CC; idx += 256) {
        const int c2 = idx / CC, d = idx - c2 * CC;
        float s = 0.f;
        #pragma unroll
        for (int c = 0; c < CC; ++c) s += ww[c2 * CC + c] * uu.a.att[c][d];
        uu.a.WA[c2][d] = s;
    }
    __syncthreads();
    // ---- phase 4: M2 = vv * WA, written fp16 directly into A2 ----
    for (int idx = tid; idx < 32 * CC; idx += 256) {
        const int e = idx / CC, d = idx - e * CC;
        float s = 0.f;
        #pragma unroll
        for (int c2 = 0; c2 < CC; ++c2) s += vw[e * 32 + c2 + 1] * uu.a.WA[c2][d];
        A2[((d >> 3) * 32 + e) * 20 + 8 + (d & 7)] =
            (short)__half_as_ushort(__float2half(s));
    }
    __syncthreads();   // att scratch dead; union free for zb2/qb2

    const int w = tid >> 6, lane = tid & 63, quad = lane >> 4, m15 = lane & 15;
    const int mt = w & 1, jbase = (w >> 1) * 8;
    const size_t zpix = (size_t)b * CC * HWSZ + (size_t)gy * WW + gx;

    // ---- hoisted geometry: gelu pixels lane+64k (k=0..5), chunk-invariant --
    int  gzo[6];   // zb2 tap base (clamped in-bounds when inactive)
    bool gvv[6];   // interior-valid (in-range AND inside image)
    #pragma unroll
    for (int k = 0; k < 6; ++k) {
        const int p = lane + 64 * k;
        const int hy = p / 18, hx = p - hy * 18;
        const bool inr = (p < 324);
        gzo[k] = inr ? (hy * 20 + hx) : 0;
        gvv[k] = inr && ((unsigned)(ty0 + hy - 1) < (unsigned)HH) &&
                 ((unsigned)(tx0 + hx - 1) < (unsigned)WW);
    }
    // staging geometry: thread covers (row shy, col-pair shx2) if tid < 200
    const bool sact = (tid < 200);
    const int shy = tid / 10, shx2 = (tid - shy * 10) * 2;
    const int szy = ty0 + shy - 2, szx = tx0 + shx2 - 2;
    const bool sv = sact && ((unsigned)szy < (unsigned)HH) &&
                    ((unsigned)szx < (unsigned)WW);
    const long sgoff = (long)szy * WW + szx;        // used only when sv
    const int zwo = shy * 20 + shx2;                // zb2 write offset (even)
    const unsigned short* z2u = (const unsigned short*)z2;

    v4f acc[8];
    #pragma unroll
    for (int jj = 0; jj < 8; ++jj) acc[jj] = (v4f){0.f, 0.f, 0.f, 0.f};

    // full stage (load + LDS write) for chunk 0 only
    auto stage = [&](int ci) {
        #pragma unroll
        for (int pr = 0; pr < 4; ++pr) {
            const int ch0 = ci * 8 + 2 * pr, ch1 = ch0 + 1;
            unsigned wa = 0, wb2 = 0;
            if (sv) {
                wa = *(const unsigned*)(z2u + (size_t)(b * CC + ch0) * HWSZ + sgoff);
                if (ch1 < 31)
                    wb2 = *(const unsigned*)(z2u + (size_t)(b * CC + ch1) * HWSZ + sgoff);
            }
            const unsigned u0 = (wa & 0xFFFFu) | (wb2 << 16);        // px
            const unsigned u1 = (wa >> 16) | (wb2 & 0xFFFF0000u);    // px+1
            if (sact) {
                uint2 st; st.x = u0; st.y = u1;
                *(uint2*)&uu.s.zb2[pr][zwo] = st;
            }
        }
    };

    stage(0);

    unsigned pre[8];   // in-flight staging registers for chunk ci+1

    for (int ci = 0; ci < 4; ++ci) {
        __syncthreads();   // zb2(ci) staged; Ub free (prev MFMA complete)
        // issue chunk ci+1 loads NOW -- latency hides under gelu + U-build
        if (ci < 3) {
            #pragma unroll
            for (int pr = 0; pr < 4; ++pr) {
                const int ch0 = (ci + 1) * 8 + 2 * pr, ch1 = ch0 + 1;
                pre[2 * pr] = 0; pre[2 * pr + 1] = 0;
                if (sv) {
                    pre[2 * pr] = *(const unsigned*)(z2u + (size_t)(b * CC + ch0) * HWSZ + sgoff);
                    if (ch1 < 31)
                        pre[2 * pr + 1] = *(const unsigned*)(z2u + (size_t)(b * CC + ch1) * HWSZ + sgoff);
                }
            }
        }
        // q = gelu(dw3(z2, pe1)): wave w = pair w, packed conv, f32 gelu
        {
            const int pr = w;
            unsigned wv2[9];
            #pragma unroll
            for (int t = 0; t < 9; ++t) wv2[t] = W1h[ci * 36 + t * 4 + pr];
            #pragma unroll
            for (int k = 0; k < 6; ++k) {
                const int p = lane + 64 * k;
                if (k < 5 || p < 324) {
                    unsigned qo = 0;
                    if (gvv[k]) {
                        __half2 s2h = __float2half2_rn(0.f);
                        #pragma unroll
                        for (int dy = 0; dy < 3; ++dy)
                            #pragma unroll
                            for (int dx = 0; dx < 3; ++dx)
                                s2h = __hfma2(*(const __half2*)&wv2[dy * 3 + dx],
                                              *(const __half2*)&uu.s.zb2[pr][gzo[k] + dy * 20 + dx],
                                              s2h);
                        const float2 f = __half22float2(s2h);
                        const float q0 = fast_gelu(f.x), q1 = fast_gelu(f.y);
                        qo = (unsigned)__half_as_ushort(__float2half(q0))
                           | ((unsigned)__half_as_ushort(__float2half(q1)) << 16);
                    }
                    uu.s.qb2[pr][p] = qo;
                }
            }
        }
        __syncthreads();
        // pos = dw3(q, pe2) packed; U row: [pos+z (8) | raw z2 half2 (8)]
        {
            __half2 pos2[4];
            #pragma unroll
            for (int pr = 0; pr < 4; ++pr) pos2[pr] = __float2half2_rn(0.f);
            #pragma unroll
            for (int dy = 0; dy < 3; ++dy)
                #pragma unroll
                for (int dx = 0; dx < 3; ++dx) {
                    const int tap = dy * 3 + dx;
                    const int qoff = (ty + dy) * 18 + (tx + dx);
                    #pragma unroll
                    for (int pr = 0; pr < 4; ++pr) {
                        const unsigned wq = W2h[ci * 36 + tap * 4 + pr];
                        pos2[pr] = __hfma2(*(const __half2*)&wq,
                                           *(const __half2*)&uu.s.qb2[pr][qoff], pos2[pr]);
                    }
                }
            unsigned tpk[4], zc[4];
            const int ctr = (ty + 2) * 20 + (tx + 2);
            #pragma unroll
            for (int pr = 0; pr < 4; ++pr) {
                zc[pr] = uu.s.zb2[pr][ctr];
                const int ch0 = ci * 8 + 2 * pr, ch1 = ch0 + 1;
                const float2 pf = __half22float2(pos2[pr]);
                const float t0 = pf.x + z[zpix + (size_t)ch0 * HWSZ];
                float t1 = 0.f;
                if (ch1 < 31) t1 = pf.y + z[zpix + (size_t)ch1 * HWSZ];
                tpk[pr] = (unsigned)__half_as_ushort(__float2half(t0))
                        | ((unsigned)__half_as_ushort(__float2half(t1)) << 16);
            }
            int* ub = (int*)&Ub[tid * 20];
            int2 s0, s1, s2, s3;
            s0.x = (int)tpk[0]; s0.y = (int)tpk[1];
            s1.x = (int)tpk[2]; s1.y = (int)tpk[3];
            s2.x = (int)zc[0];  s2.y = (int)zc[1];
            s3.x = (int)zc[2];  s3.y = (int)zc[3];
            ((int2*)ub)[0] = s0;
            ((int2*)ub)[1] = s1;
            ((int2*)ub)[2] = s2;
            ((int2*)ub)[3] = s3;
        }
        __syncthreads();   // Ub(ci) ready; zb2 consumed
        // chunk ci+1 prefetch lands: transpose regs -> zb2 (overlaps MFMA)
        if (ci < 3 && sact) {
            #pragma unroll
            for (int pr = 0; pr < 4; ++pr) {
                const unsigned wa = pre[2 * pr], wb2 = pre[2 * pr + 1];
                uint2 st;
                st.x = (wa & 0xFFFFu) | (wb2 << 16);
                st.y = (wa >> 16) | (wb2 & 0xFFFF0000u);
                *(uint2*)&uu.s.zb2[pr][zwo] = st;
            }
        }
        // partial epilogue GEMM: acc += A2c[ci] @ U(ci)   (K=16 fp16 MFMA)
        {
            const v4h a = *(const v4h*)&A2[(ci * 32 + mt * 16 + m15) * 20 + quad * 4];
            #pragma unroll
            for (int jj = 0; jj < 8; ++jj) {
                const int p = (jbase + jj) * 16 + m15;
                const v4h bv = *(const v4h*)&Ub[p * 20 + quad * 4];
                acc[jj] = __builtin_amdgcn_mfma_f32_16x16x16f16(a, bv, acc[jj], 0, 0, 0);
            }
        }
    }

    // ---- epilogue: out = acc + vb2 + vw0*x ----
    {
        float vb2r[4], vw0[4];
        #pragma unroll
        for (int r = 0; r < 4; ++r) {
            const int e = mt * 16 + quad * 4 + r;
            vb2r[r] = vb2s[e];
            vw0[r]  = vw[e * 32];
        }
        #pragma unroll
        for (int jj = 0; jj < 8; ++jj) {
            const int p = (jbase + jj) * 16 + m15;
            const int py = p >> 4, px = p & 15;
            const int ogy = ty0 + py, ogx = tx0 + px;
            const float xv = x[(size_t)b * HWSZ + (size_t)ogy * WW + ogx];
            const size_t obase = (size_t)b * 32 * HWSZ + (size_t)ogy * WW + ogx;
            #pragma unroll
            for (int r = 0; r < 4; ++r) {
                const int e = mt * 16 + quad * 4 + r;
                out[obase + (size_t)e * HWSZ] = acc[jj][r] + vb2r[r] + vw0[r] * xv;
            }
        }
    }
}

// ---------------------------------------------------------------------------
extern "C" void kernel_launch(void* const* d_in, const int* in_sizes, int n_in,
                              void* d_out, int out_size, void* d_ws, size_t ws_size,
                              hipStream_t stream)
{
    (void)in_sizes; (void)n_in; (void)out_size; (void)ws_size;

    const float* x    = (const float*)d_in[0];
    const float* z    = (const float*)d_in[1];
    const float* nx_b = (const float*)d_in[3];
    const float* nz_w = (const float*)d_in[4];
    const float* nz_b = (const float*)d_in[5];
    const float* t1w  = (const float*)d_in[6];
    const float* t1b  = (const float*)d_in[7];
    const float* t2w  = (const float*)d_in[8];
    const float* t2b  = (const float*)d_in[9];
    const float* p1w  = (const float*)d_in[10];
    const float* p1b  = (const float*)d_in[11];
    const float* p2w  = (const float*)d_in[12];
    const float* p2b  = (const float*)d_in[13];
    const float* g1w  = (const float*)d_in[14];
    const float* g1b  = (const float*)d_in[15];
    const float* g2w  = (const float*)d_in[16];
    const float* g2b  = (const float*)d_in[17];
    const float* ww   = (const float*)d_in[18];
    const float* wb   = (const float*)d_in[19];
    const float* vw   = (const float*)d_in[20];
    const float* vb   = (const float*)d_in[21];
    const float* pe1w = (const float*)d_in[22];
    const float* pe2w = (const float*)d_in[23];

    __half* z2   = (__half*)d_ws;
    float* stats = (float*)((char*)d_ws + Z2F * sizeof(__half));

    hipMemsetAsync(stats, 0, 1240 * sizeof(float), stream);

    dim3 grid(WW / 16, HH / 16, BN);
    dim3 blk(256);

    blockNL_k_stage1<<<grid, blk, 0, stream>>>(z, nz_w, nz_b, t1w, t1b, t2w, t2b,
                                               g1w, g1b, g2w, g2b, z2, stats);
    blockNL_k_out<<<grid, blk, 0, stream>>>(x, z, nx_b, p1w, p1b, p2w, p2b,
                                            ww, wb, vw, vb, pe1w, pe2w,
                                            z2, stats, (float*)d_out);
}

// Round 19
// 514.161 us; speedup vs baseline: 1.0152x; 1.0152x over previous
//
#include <hip/hip_runtime.h>
#include <hip/hip_fp16.h>
#include <math.h>

// Problem constants
#define BN 4
#define CC 31
#define HH 512
#define WW 512
#define HWSZ 262144  // 512*512

// Workspace: z2 field (b,c,h,w) fp16, then float stats region.
static const size_t Z2F = (size_t)BN * CC * HWSZ;
#define T_OFF   0
#define SSQ_OFF 124
#define R0_OFF  248
#define RL_OFF  372
#define C0_OFF  496
#define CL_OFF  620
#define COR_OFF 744

typedef short v8s __attribute__((ext_vector_type(8)));      // 8 bf16/f16 bits
typedef _Float16 v8h __attribute__((ext_vector_type(8)));   // 8 f16
typedef float v4f __attribute__((ext_vector_type(4)));      // 4 f32 (C/D frag)
typedef _Float16 v4h __attribute__((ext_vector_type(4)));   // 4 f16 (K=16 frag)

__device__ __forceinline__ short f2bf(float f) {   // f32 -> bf16 (RNE)
    unsigned u = __float_as_uint(f);
    return (short)((u + 0x7FFFu + ((u >> 16) & 1u)) >> 16);
}

// gelu(s) with Abramowitz-Stegun 7.1.26 erf (max abs err 1.5e-7 -- far below
// fp16 quantum). Straight-line: rcp + 5 FMA + v_exp, no branches.
__device__ __forceinline__ float fast_gelu(float s) {
    const float a  = fabsf(s) * 0.70710678118654752f;
    const float t  = __builtin_amdgcn_rcpf(1.f + 0.3275911f * a);
    float p = 1.061405429f;
    p = p * t - 1.453152027f;
    p = p * t + 1.421413741f;
    p = p * t - 0.284496736f;
    p = p * t + 0.254829592f;
    const float e  = __expf(-a * a);
    const float er = copysignf(1.f - p * t * e, s);
    return 0.5f * s * (1.f + er);
}

// XCD-aware swizzle: each XCD gets a contiguous 512-tile region.
__device__ __forceinline__ void swizzle_tile(int& b, int& ty0, int& tx0) {
    const int lid = blockIdx.x + 32 * blockIdx.y + 1024 * blockIdx.z;
    const int vid = ((lid & 7) << 9) + (lid >> 3);
    b = vid >> 10;
    const int rem = vid & 1023;
    ty0 = (rem >> 5) << 4;
    tx0 = (rem & 31) << 4;
}

// ---------------------------------------------------------------------------
// Kernel A: 16x16 tile. Zb aliased on Ff; grid-limited 4 blocks/CU. Phase-1
// LN load loop split from accumulate (round-15/17 winner, reverted from the
// neutral round-18 dual-pixel batch).
// ---------------------------------------------------------------------------
__global__ __launch_bounds__(256, 4) void blockNL_k_stage1(
    const float* __restrict__ z,
    const float* __restrict__ nz_w, const float* __restrict__ nz_b,
    const float* __restrict__ t1w, const float* __restrict__ t1b,
    const float* __restrict__ t2w, const float* __restrict__ t2b,
    const float* __restrict__ g1w, const float* __restrict__ g1b,
    const float* __restrict__ g2w, const float* __restrict__ g2b,
    __half* __restrict__ z2out, float* __restrict__ stats)
{
    __shared__ __align__(16) short Vb[324 * 32];   // LN halo, bf16 [px][32ch] 20736 B
    __shared__ __align__(16) short Wp[16 * 32];    // per-pass 1x1 W bf16      1024 B
    __shared__ __align__(16) union {
        short Ff[324 * 16];                        // per-pass field f16      10368 B
        short Zb[16 * 264];                        // per-pass z1 f16 stats    8448 B
    } uf;
    __shared__ __align__(16) short Wd[10 * 16];    // per-pass dw3 W+bias f16   320 B

    const int tid = threadIdx.x;
    int b, ty0, tx0;
    swizzle_tile(b, ty0, tx0);

    const int w = tid >> 6, lane = tid & 63, quad = lane >> 4, m15 = lane & 15;
    const int ty = tid >> 4, tx = tid & 15;
    const int gy = ty0 + ty, gx = tx0 + tx;

    // ---- phase 1: stage LN field (bf16) into Vb ----
    for (int hp = tid; hp < 324; hp += 256) {
        const int hy = hp / 18, hx = hp - hy * 18;
        const int zy = ty0 + hy - 1, zx = tx0 + hx - 1;
        const bool valid = ((unsigned)zy < (unsigned)HH) && ((unsigned)zx < (unsigned)WW);
        int pk[16];
        if (valid) {
            const float* zp = z + (size_t)b * CC * HWSZ + (size_t)zy * WW + zx;
            float v[CC];
            #pragma unroll
            for (int c = 0; c < CC; ++c) v[c] = zp[(size_t)c * HWSZ];  // all loads in flight
            float mu = 0.f;
            #pragma unroll
            for (int c = 0; c < CC; ++c) mu += v[c];
            mu *= (1.f / 31.f);
            float var = 0.f;
            #pragma unroll
            for (int c = 0; c < CC; ++c) { float d = v[c] - mu; v[c] = d; var += d * d; }
            var *= (1.f / 31.f);
            const float rs = rsqrtf(var + 1e-5f);
            #pragma unroll
            for (int c = 0; c < CC; ++c) v[c] = v[c] * rs * nz_w[c] + nz_b[c];
            #pragma unroll
            for (int i = 0; i < 15; ++i)
                asm("v_cvt_pk_bf16_f32 %0, %1, %2"
                    : "=v"(pk[i]) : "v"(v[2 * i]), "v"(v[2 * i + 1]));
            asm("v_cvt_pk_bf16_f32 %0, %1, %2"
                : "=v"(pk[15]) : "v"(v[30]), "v"(0.f));
        } else {
            #pragma unroll
            for (int i = 0; i < 16; ++i) pk[i] = 0;
        }
        int* dst = (int*)&Vb[hp * 32];
        #pragma unroll
        for (int q = 0; q < 4; ++q) {
            int4 t; t.x = pk[q*4]; t.y = pk[q*4+1]; t.z = pk[q*4+2]; t.w = pk[q*4+3];
            ((int4*)dst)[q] = t;
        }
    }

    // per-pass 1x1 weight tile: rows ct*16..ct*16+15 of t1w (p<2) or g1w
    auto wbuild = [&](int p) {
        const float* W1 = (p >= 2) ? g1w : t1w;
        const int ct = p & 1;
        const int m = tid >> 4, kp = tid & 15;
        const int gr = ct * 16 + m;
        const int k0 = 2 * kp, k1 = k0 + 1;
        float w0 = 0.f, w1 = 0.f;
        if (gr < CC) {
            if (k0 < CC) w0 = W1[gr * CC + k0];
            if (k1 < CC) w1 = W1[gr * CC + k1];
        }
        ((int*)Wp)[m * 16 + kp] =
            (int)((unsigned short)f2bf(w0) | ((unsigned)(unsigned short)f2bf(w1) << 16));
    };

    // per-pass dw3 weight/bias table (fp16): rows 0-8 = taps, row 9 = bias
    auto wdbuild = [&](int p) {
        if (tid < 160) {
            const float* W3 = (p >= 2) ? g2w : t2w;
            const float* B3 = (p >= 2) ? g2b : t2b;
            const int tap = tid >> 4, r = tid & 15;
            const int ch = (p & 1) * 16 + r;
            float v = 0.f;
            if (ch < CC) v = (tap < 9) ? W3[ch * 9 + tap] : B3[ch];
            Wd[tap * 16 + r] = (short)__half_as_ushort(__float2half(v));
        }
    };

    // MFMA matvec: field[px][16] f16; half-index XOR swizzle keyed on px bit 2
    auto mfma_pass = [&](int p) {
        const int ct = p & 1;
        const float* B1 = (p >= 2) ? g1b : t1b;
        const v8s afrag = *(const v8s*)&Wp[m15 * 32 + quad * 8];
        float bias[4];
        #pragma unroll
        for (int r = 0; r < 4; ++r) {
            const int row = ct * 16 + quad * 4 + r;
            bias[r] = (row < CC) ? B1[row] : 0.f;
        }
        for (int j = w; j < 21; j += 4) {
            const int px = j * 16 + m15;
            const int pc = (px < 324) ? px : 323;   // clamp tail (garbage, unstored)
            const v8s bfrag = *(const v8s*)&Vb[pc * 32 + quad * 8];
            v4f acc = {0.f, 0.f, 0.f, 0.f};
            acc = __builtin_amdgcn_mfma_f32_16x16x32_bf16(afrag, bfrag, acc, 0, 0, 0);
            if (px < 324) {
                unsigned d0 = (unsigned)__half_as_ushort(__float2half(acc[0] + bias[0]))
                            | ((unsigned)__half_as_ushort(__float2half(acc[1] + bias[1])) << 16);
                unsigned d1 = (unsigned)__half_as_ushort(__float2half(acc[2] + bias[2]))
                            | ((unsigned)__half_as_ushort(__float2half(acc[3] + bias[3])) << 16);
                const int half = (quad >> 1) ^ ((px >> 2) & 1);
                int2 st; st.x = (int)d0; st.y = (int)d1;
                *(int2*)&uf.Ff[px * 16 + half * 8 + (quad & 1) * 4] = st;
            }
        }
    };

    // dw3 compute (packed fp16): accv[i] = half2 of channels (2i, 2i+1)
    auto dw3_compute = [&](__half2* accv) {
        {
            const v8s b0 = *(const v8s*)&Wd[9 * 16 + 0];
            const v8s b1 = *(const v8s*)&Wd[9 * 16 + 8];
            #pragma unroll
            for (int i = 0; i < 4; ++i) {
                accv[i]     = ((const __half2*)&b0)[i];
                accv[4 + i] = ((const __half2*)&b1)[i];
            }
        }
        #pragma unroll
        for (int dy = 0; dy < 3; ++dy)
            #pragma unroll
            for (int dx = 0; dx < 3; ++dx) {
                const int tap = dy * 3 + dx;
                const int hp = (ty + dy) * 18 + (tx + dx);
                const int sel = (hp >> 2) & 1;
                const v8s f0 = *(const v8s*)&uf.Ff[hp * 16 + sel * 8];        // ch 0-7
                const v8s f1 = *(const v8s*)&uf.Ff[hp * 16 + (sel ^ 1) * 8];  // ch 8-15
                const v8s w0 = *(const v8s*)&Wd[tap * 16 + 0];
                const v8s w1 = *(const v8s*)&Wd[tap * 16 + 8];
                #pragma unroll
                for (int i = 0; i < 4; ++i) {
                    accv[i]     = __hfma2(((const __half2*)&w0)[i],
                                          ((const __half2*)&f0)[i], accv[i]);
                    accv[4 + i] = __hfma2(((const __half2*)&w1)[i],
                                          ((const __half2*)&f1)[i], accv[4 + i]);
                }
            }
    };

    // T-pass write half: Zb (aliased on Ff -- caller barriers first) + edges
    auto dw3_writeT = [&](int ct, const __half2* accv) {
        #pragma unroll
        for (int i = 0; i < 8; ++i) {
            const unsigned u = *(const unsigned*)&accv[i];
            uf.Zb[(2 * i) * 264 + tid]     = (short)(u & 0xFFFFu);
            uf.Zb[(2 * i + 1) * 264 + tid] = (short)(u >> 16);
        }
        const bool top = (gy == 0), bot = (gy == HH - 1);
        const bool lef = (gx == 0), rig = (gx == WW - 1);
        if (top | bot | lef | rig) {
            #pragma unroll
            for (int r = 0; r < 16; ++r) {
                const int ch = ct * 16 + r;
                if (ch < CC) {
                    const unsigned u = *(const unsigned*)&accv[r >> 1];
                    const float sT = __half2float(__ushort_as_half(
                        (unsigned short)((r & 1) ? (u >> 16) : (u & 0xFFFFu))));
                    if (top) atomicAdd(&stats[R0_OFF + b * CC + ch], sT);
                    if (bot) atomicAdd(&stats[RL_OFF + b * CC + ch], sT);
                    if (lef) atomicAdd(&stats[C0_OFF + b * CC + ch], sT);
                    if (rig) atomicAdd(&stats[CL_OFF + b * CC + ch], sT);
                    if ((top || bot) && (lef || rig))
                        stats[COR_OFF + (b * CC + ch) * 4 +
                              (bot ? 2 : 0) + (rig ? 1 : 0)] = sT;
                }
            }
        }
    };

    // G-pass write half: z2 field to global (no LDS writes)
    auto dw3_writeG = [&](int ct, const __half2* accv) {
        const size_t zbase = (size_t)b * CC * HWSZ + (size_t)gy * WW + gx;
        #pragma unroll
        for (int i = 0; i < 8; ++i) {
            const unsigned u = *(const unsigned*)&accv[i];
            const int ch0 = ct * 16 + 2 * i, ch1 = ch0 + 1;
            z2out[zbase + (size_t)ch0 * HWSZ] =
                __ushort_as_half((unsigned short)(u & 0xFFFFu));
            if (ch1 < CC)
                z2out[zbase + (size_t)ch1 * HWSZ] =
                    __ushort_as_half((unsigned short)(u >> 16));
        }
    };

    // stats: waves 0,1 = sums (ks halves), waves 2,3 = ssq (ks halves); f16
    auto stats_pass = [&](int ct) {
        const bool dosq = (w >> 1);
        const int kh = w & 1;
        v8h onesh;
        #pragma unroll
        for (int i = 0; i < 8; ++i) onesh[i] = (_Float16)1.f;
        v4f acc = {0.f, 0.f, 0.f, 0.f};
        #pragma unroll
        for (int i = 0; i < 4; ++i) {
            const int ks = kh * 4 + i;
            const v8h bf = *(const v8h*)&uf.Zb[m15 * 264 + ks * 32 + quad * 8];
            acc = __builtin_amdgcn_mfma_f32_16x16x32_f16(dosq ? bf : onesh, bf, acc, 0, 0, 0);
        }
        if (!dosq) {
            if (quad == 0) {
                const int ch = ct * 16 + m15;
                if (ch < CC) atomicAdd(&stats[T_OFF + b * CC + ch], acc[0]);
            }
        } else {
            if ((m15 >> 2) == quad) {   // diagonal lane for n = m15
                const int r = m15 & 3;
                const int ch = ct * 16 + m15;
                if (ch < CC) atomicAdd(&stats[SSQ_OFF + b * CC + ch], acc[r]);
            }
        }
    };

    __half2 accv[8];

    wbuild(0); wdbuild(0);
    __syncthreads();
    mfma_pass(0);
    __syncthreads();
    dw3_compute(accv);           // reads Ff(0)
    __syncthreads();             // all reads done -> safe to alias-write
    dw3_writeT(0, accv);
    __syncthreads();
    stats_pass(0); wbuild(1); wdbuild(1);
    __syncthreads();
    mfma_pass(1);                // rewrites Ff (clobbers Zb(0) -- consumed)
    __syncthreads();
    dw3_compute(accv);
    __syncthreads();
    dw3_writeT(1, accv);
    __syncthreads();
    stats_pass(1); wbuild(2); wdbuild(2);
    __syncthreads();
    mfma_pass(2);
    __syncthreads();
    dw3_compute(accv); dw3_writeG(2, accv); wbuild(3);
    __syncthreads();
    mfma_pass(3); wdbuild(3);
    __syncthreads();
    dw3_compute(accv); dw3_writeG(3, accv);
}

// ---------------------------------------------------------------------------
// Kernel C: channel-pair-packed fp16 data plane + fused attention prologue +
// in-loop T14 staging split. NEW: the U-build's 8 strided z loads are also
// prefetched at the loop top (issued next to the staging prefetch, consumed
// in U-build after the gelu phase -- same proven mechanism as round 17).
// LDS: 11584(uu) + 10240(Ub) + 5120(A2) + 1152(W) + 128(vb2s) = 28224 B.
// ---------------------------------------------------------------------------
__global__ __launch_bounds__(256, 4) void blockNL_k_out(
    const float* __restrict__ x, const float* __restrict__ z,
    const float* __restrict__ nx_b,
    const float* __restrict__ p1w, const float* __restrict__ p1b,
    const float* __restrict__ p2w, const float* __restrict__ p2b,
    const float* __restrict__ ww,  const float* __restrict__ wb,
    const float* __restrict__ vw,  const float* __restrict__ vb,
    const float* __restrict__ pe1w, const float* __restrict__ pe2w,
    const __half* __restrict__ z2, const float* __restrict__ stats,
    float* __restrict__ out)
{
    __shared__ __align__(16) union {
        struct {
            unsigned zb2[4][400];                   // half2 [pair][20x20 px]
            unsigned qb2[4][324];                   // half2 [pair][18x18 px]
        } s;
        struct {
            float x1v[CC][9];
            float dxs[CC];
            float att[CC][CC];
            float WA[CC][CC];
        } a;
    } uu;
    __shared__ __align__(16) short Ub[256 * 20];    // per-chunk U [px][16+pad] f16
    __shared__ __align__(16) short A2[4 * 32 * 20]; // per-chunk A [ci][e][16+pad] f16
    __shared__ unsigned W1h[144];                   // pe1w half2 [ci][tap][pair]
    __shared__ unsigned W2h[144];                   // pe2w half2 [ci][tap][pair]
    __shared__ float vb2s[32];                      // folded v-bias

    const int tid = threadIdx.x;
    int b, ty0, tx0;
    swizzle_tile(b, ty0, tx0);
    const int ty = tid >> 4, tx = tid & 15;
    const int gy = ty0 + ty, gx = tx0 + tx;

    // ---- fused attention prologue, phase 1: x1v/dxs, vb2, A2 init, W tables
    {
        const float cnt[9] = {1.f, 510.f, 1.f, 510.f, 260100.f, 510.f, 1.f, 510.f, 1.f};
        if (tid < CC) {
            const float a = nx_b[0];
            const float u = p1w[tid] * a + p1b[tid];
            float w9[9];
            #pragma unroll
            for (int k = 0; k < 9; ++k) w9[k] = p2w[tid * 9 + k];
            float ssq = 0.f;
            #pragma unroll
            for (int ry = 0; ry < 3; ++ry) {
                #pragma unroll
                for (int rx = 0; rx < 3; ++rx) {
                    float wsum = 0.f;
                    #pragma unroll
                    for (int ky = 0; ky < 3; ++ky) {
                        #pragma unroll
                        for (int kx = 0; kx < 3; ++kx) {
                            const bool okr = (ry == 1) || (ry == 0 && ky >= 1) || (ry == 2 && ky <= 1);
                            const bool okc = (rx == 1) || (rx == 0 && kx >= 1) || (rx == 2 && kx <= 1);
                            if (okr && okc) wsum += w9[ky * 3 + kx];
                        }
                    }
                    const float val = u * wsum + p2b[tid];
                    uu.a.x1v[tid][ry * 3 + rx] = val;
                    ssq += cnt[ry * 3 + rx] * val * val;
                }
            }
            uu.a.dxs[tid] = fmaxf(sqrtf(ssq), 1e-12f);
        }
        if (tid >= 64 && tid < 96) {
            const int e = tid - 64;
            float s = vb[e];
            #pragma unroll
            for (int c = 0; c < CC; ++c) s += vw[e * 32 + c + 1] * wb[c];
            vb2s[e] = s;
        }
    }
    // A2 init: k<8 -> vw[e][ci*8+k]; k>=8 -> 0 (M2 overwrites d<31 slots later)
    for (int idx = tid; idx < 2048; idx += 256) {
        const int ci = idx >> 9, e = (idx >> 4) & 31, k = idx & 15;
        const int ch = ci * 8 + (k & 7);
        float v = 0.f;
        if (k < 8 && ch < 31) v = vw[e * 32 + 1 + ch];
        A2[(ci * 32 + e) * 20 + k] = (short)__half_as_ushort(__float2half(v));
    }
    // weight tables: [ci*36 + tap*4 + pair] = half2(w[ch0], w[ch1])
    for (int idx = tid; idx < 288; idx += 256) {
        const int t = (idx >= 144);
        const int r = idx - t * 144;
        const int ci = r / 36, rem = r - ci * 36;
        const int tap = rem >> 2, pr = rem & 3;
        const int ch0 = ci * 8 + 2 * pr, ch1 = ch0 + 1;
        const float* Ws = t ? pe2w : pe1w;
        const float a = Ws[ch0 * 9 + tap];                    // ch0 <= 30
        const float bb = (ch1 < 31) ? Ws[ch1 * 9 + tap] : 0.f;
        const unsigned u = (unsigned)__half_as_ushort(__float2half(a))
                         | ((unsigned)__half_as_ushort(__float2half(bb)) << 16);
        (t ? W2h : W1h)[r] = u;
    }
    __syncthreads();
    // ---- phase 2: att rows (thread c owns row c; softmax in f32) ----
    if (tid < CC) {
        const int c = tid;
        const float Tt  = stats[T_OFF  + b * CC + c];
        const float sq  = stats[SSQ_OFF + b * CC + c];
        const float r0  = stats[R0_OFF + b * CC + c];
        const float rL  = stats[RL_OFF + b * CC + c];
        const float c0  = stats[C0_OFF + b * CC + c];
        const float cL  = stats[CL_OFF + b * CC + c];
        const float k00 = stats[COR_OFF + (b * CC + c) * 4 + 0];
        const float k01 = stats[COR_OFF + (b * CC + c) * 4 + 1];
        const float k10 = stats[COR_OFF + (b * CC + c) * 4 + 2];
        const float k11 = stats[COR_OFF + (b * CC + c) * 4 + 3];
        float T[9];
        T[0] = k00; T[2] = k01; T[6] = k10; T[8] = k11;
        T[1] = r0 - k00 - k01;
        T[7] = rL - k10 - k11;
        T[3] = c0 - k00 - k10;
        T[5] = cL - k01 - k11;
        T[4] = Tt - r0 - rL - c0 - cL + k00 + k01 + k10 + k11;
        const float dz = fmaxf(sqrtf(sq), 1e-12f);

        float Arow[CC];
        float mx = -3.4e38f;
        #pragma unroll
        for (int d = 0; d < CC; ++d) {
            float s = 0.f;
            #pragma unroll
            for (int r = 0; r < 9; ++r) s += T[r] * uu.a.x1v[d][r];
            s = s / (dz * uu.a.dxs[d]);
            Arow[d] = s;
            mx = fmaxf(mx, s);
        }
        float den = 0.f;
        #pragma unroll
        for (int d = 0; d < CC; ++d) { float e = __expf(Arow[d] - mx); Arow[d] = e; den += e; }
        const float inv = 1.f / den;
        #pragma unroll
        for (int d = 0; d < CC; ++d) uu.a.att[c][d] = Arow[d] * inv;
    }
    __syncthreads();
    // ---- phase 3: WA = ww * att  (961 dots over 256 threads) ----
    for (int idx = tid; idx < CC * CC; idx += 256) {
        const int c2 = idx / CC, d = idx - c2 * CC;
        float s = 0.f;
        #pragma unroll
        for (int c = 0; c < CC; ++c) s += ww[c2 * CC + c] * uu.a.att[c][d];
        uu.a.WA[c2][d] = s;
    }
    __syncthreads();
    // ---- phase 4: M2 = vv * WA, written fp16 directly into A2 ----
    for (int idx = tid; idx < 32 * CC; idx += 256) {
        const int e = idx / CC, d = idx - e * CC;
        float s = 0.f;
        #pragma unroll
        for (int c2 = 0; c2 < CC; ++c2) s += vw[e * 32 + c2 + 1] * uu.a.WA[c2][d];
        A2[((d >> 3) * 32 + e) * 20 + 8 + (d & 7)] =
            (short)__half_as_ushort(__float2half(s));
    }
    __syncthreads();   // att scratch dead; union free for zb2/qb2

    const int w = tid >> 6, lane = tid & 63, quad = lane >> 4, m15 = lane & 15;
    const int mt = w & 1, jbase = (w >> 1) * 8;
    const size_t zpix = (size_t)b * CC * HWSZ + (size_t)gy * WW + gx;

    // ---- hoisted geometry: gelu pixels lane+64k (k=0..5), chunk-invariant --
    int  gzo[6];   // zb2 tap base (clamped in-bounds when inactive)
    bool gvv[6];   // interior-valid (in-range AND inside image)
    #pragma unroll
    for (int k = 0; k < 6; ++k) {
        const int p = lane + 64 * k;
        const int hy = p / 18, hx = p - hy * 18;
        const bool inr = (p < 324);
        gzo[k] = inr ? (hy * 20 + hx) : 0;
        gvv[k] = inr && ((unsigned)(ty0 + hy - 1) < (unsigned)HH) &&
                 ((unsigned)(tx0 + hx - 1) < (unsigned)WW);
    }
    // staging geometry: thread covers (row shy, col-pair shx2) if tid < 200
    const bool sact = (tid < 200);
    const int shy = tid / 10, shx2 = (tid - shy * 10) * 2;
    const int szy = ty0 + shy - 2, szx = tx0 + shx2 - 2;
    const bool sv = sact && ((unsigned)szy < (unsigned)HH) &&
                    ((unsigned)szx < (unsigned)WW);
    const long sgoff = (long)szy * WW + szx;        // used only when sv
    const int zwo = shy * 20 + shx2;                // zb2 write offset (even)
    const unsigned short* z2u = (const unsigned short*)z2;

    v4f acc[8];
    #pragma unroll
    for (int jj = 0; jj < 8; ++jj) acc[jj] = (v4f){0.f, 0.f, 0.f, 0.f};

    // full stage (load + LDS write) for chunk 0 only
    auto stage = [&](int ci) {
        #pragma unroll
        for (int pr = 0; pr < 4; ++pr) {
            const int ch0 = ci * 8 + 2 * pr, ch1 = ch0 + 1;
            unsigned wa = 0, wb2 = 0;
            if (sv) {
                wa = *(const unsigned*)(z2u + (size_t)(b * CC + ch0) * HWSZ + sgoff);
                if (ch1 < 31)
                    wb2 = *(const unsigned*)(z2u + (size_t)(b * CC + ch1) * HWSZ + sgoff);
            }
            const unsigned u0 = (wa & 0xFFFFu) | (wb2 << 16);        // px
            const unsigned u1 = (wa >> 16) | (wb2 & 0xFFFF0000u);    // px+1
            if (sact) {
                uint2 st; st.x = u0; st.y = u1;
                *(uint2*)&uu.s.zb2[pr][zwo] = st;
            }
        }
    };

    stage(0);

    unsigned pre[8];   // in-flight staging registers for chunk ci+1
    float zpre[8];     // prefetched z values for chunk ci's U-build

    for (int ci = 0; ci < 4; ++ci) {
        __syncthreads();   // zb2(ci) staged; Ub free (prev MFMA complete)
        // issue chunk ci+1 staging loads + chunk ci's U-build z loads NOW --
        // latency hides under the gelu phase
        if (ci < 3) {
            #pragma unroll
            for (int pr = 0; pr < 4; ++pr) {
                const int ch0 = (ci + 1) * 8 + 2 * pr, ch1 = ch0 + 1;
                pre[2 * pr] = 0; pre[2 * pr + 1] = 0;
                if (sv) {
                    pre[2 * pr] = *(const unsigned*)(z2u + (size_t)(b * CC + ch0) * HWSZ + sgoff);
                    if (ch1 < 31)
                        pre[2 * pr + 1] = *(const unsigned*)(z2u + (size_t)(b * CC + ch1) * HWSZ + sgoff);
                }
            }
        }
        #pragma unroll
        for (int r = 0; r < 8; ++r) {
            const int ch = ci * 8 + r;
            zpre[r] = (ch < 31) ? z[zpix + (size_t)ch * HWSZ] : 0.f;
        }
        // q = gelu(dw3(z2, pe1)): wave w = pair w, packed conv, f32 gelu
        {
            const int pr = w;
            unsigned wv2[9];
            #pragma unroll
            for (int t = 0; t < 9; ++t) wv2[t] = W1h[ci * 36 + t * 4 + pr];
            #pragma unroll
            for (int k = 0; k < 6; ++k) {
                const int p = lane + 64 * k;
                if (k < 5 || p < 324) {
                    unsigned qo = 0;
                    if (gvv[k]) {
                        __half2 s2h = __float2half2_rn(0.f);
                        #pragma unroll
                        for (int dy = 0; dy < 3; ++dy)
                            #pragma unroll
                            for (int dx = 0; dx < 3; ++dx)
                                s2h = __hfma2(*(const __half2*)&wv2[dy * 3 + dx],
                                              *(const __half2*)&uu.s.zb2[pr][gzo[k] + dy * 20 + dx],
                                              s2h);
                        const float2 f = __half22float2(s2h);
                        const float q0 = fast_gelu(f.x), q1 = fast_gelu(f.y);
                        qo = (unsigned)__half_as_ushort(__float2half(q0))
                           | ((unsigned)__half_as_ushort(__float2half(q1)) << 16);
                    }
                    uu.s.qb2[pr][p] = qo;
                }
            }
        }
        __syncthreads();
        // pos = dw3(q, pe2) packed; U row: [pos+z (8) | raw z2 half2 (8)]
        {
            __half2 pos2[4];
            #pragma unroll
            for (int pr = 0; pr < 4; ++pr) pos2[pr] = __float2half2_rn(0.f);
            #pragma unroll
            for (int dy = 0; dy < 3; ++dy)
                #pragma unroll
                for (int dx = 0; dx < 3; ++dx) {
                    const int tap = dy * 3 + dx;
                    const int qoff = (ty + dy) * 18 + (tx + dx);
                    #pragma unroll
                    for (int pr = 0; pr < 4; ++pr) {
                        const unsigned wq = W2h[ci * 36 + tap * 4 + pr];
                        pos2[pr] = __hfma2(*(const __half2*)&wq,
                                           *(const __half2*)&uu.s.qb2[pr][qoff], pos2[pr]);
                    }
                }
            unsigned tpk[4], zc[4];
            const int ctr = (ty + 2) * 20 + (tx + 2);
            #pragma unroll
            for (int pr = 0; pr < 4; ++pr) {
                zc[pr] = uu.s.zb2[pr][ctr];
                const int ch1 = ci * 8 + 2 * pr + 1;
                const float2 pf = __half22float2(pos2[pr]);
                const float t0 = pf.x + zpre[2 * pr];
                float t1 = 0.f;
                if (ch1 < 31) t1 = pf.y + zpre[2 * pr + 1];
                tpk[pr] = (unsigned)__half_as_ushort(__float2half(t0))
                        | ((unsigned)__half_as_ushort(__float2half(t1)) << 16);
            }
            int* ub = (int*)&Ub[tid * 20];
            int2 s0, s1, s2, s3;
            s0.x = (int)tpk[0]; s0.y = (int)tpk[1];
            s1.x = (int)tpk[2]; s1.y = (int)tpk[3];
            s2.x = (int)zc[0];  s2.y = (int)zc[1];
            s3.x = (int)zc[2];  s3.y = (int)zc[3];
            ((int2*)ub)[0] = s0;
            ((int2*)ub)[1] = s1;
            ((int2*)ub)[2] = s2;
            ((int2*)ub)[3] = s3;
        }
        __syncthreads();   // Ub(ci) ready; zb2 consumed
        // chunk ci+1 prefetch lands: transpose regs -> zb2 (overlaps MFMA)
        if (ci < 3 && sact) {
            #pragma unroll
            for (int pr = 0; pr < 4; ++pr) {
                const unsigned wa = pre[2 * pr], wb2 = pre[2 * pr + 1];
                uint2 st;
                st.x = (wa & 0xFFFFu) | (wb2 << 16);
                st.y = (wa >> 16) | (wb2 & 0xFFFF0000u);
                *(uint2*)&uu.s.zb2[pr][zwo] = st;
            }
        }
        // partial epilogue GEMM: acc += A2c[ci] @ U(ci)   (K=16 fp16 MFMA)
        {
            const v4h a = *(const v4h*)&A2[(ci * 32 + mt * 16 + m15) * 20 + quad * 4];
            #pragma unroll
            for (int jj = 0; jj < 8; ++jj) {
                const int p = (jbase + jj) * 16 + m15;
                const v4h bv = *(const v4h*)&Ub[p * 20 + quad * 4];
                acc[jj] = __builtin_amdgcn_mfma_f32_16x16x16f16(a, bv, acc[jj], 0, 0, 0);
            }
        }
    }

    // ---- epilogue: out = acc + vb2 + vw0*x ----
    {
        float vb2r[4], vw0[4];
        #pragma unroll
        for (int r = 0; r < 4; ++r) {
            const int e = mt * 16 + quad * 4 + r;
            vb2r[r] = vb2s[e];
            vw0[r]  = vw[e * 32];
        }
        #pragma unroll
        for (int jj = 0; jj < 8; ++jj) {
            const int p = (jbase + jj) * 16 + m15;
            const int py = p >> 4, px = p & 15;
            const int ogy = ty0 + py, ogx = tx0 + px;
            const float xv = x[(size_t)b * HWSZ + (size_t)ogy * WW + ogx];
            const size_t obase = (size_t)b * 32 * HWSZ + (size_t)ogy * WW + ogx;
            #pragma unroll
            for (int r = 0; r < 4; ++r) {
                const int e = mt * 16 + quad * 4 + r;
                out[obase + (size_t)e * HWSZ] = acc[jj][r] + vb2r[r] + vw0[r] * xv;
            }
        }
    }
}

// ---------------------------------------------------------------------------
extern "C" void kernel_launch(void* const* d_in, const int* in_sizes, int n_in,
                              void* d_out, int out_size, void* d_ws, size_t ws_size,
                              hipStream_t stream)
{
    (void)in_sizes; (void)n_in; (void)out_size; (void)ws_size;

    const float* x    = (const float*)d_in[0];
    const float* z    = (const float*)d_in[1];
    const float* nx_b = (const float*)d_in[3];
    const float* nz_w = (const float*)d_in[4];
    const float* nz_b = (const float*)d_in[5];
    const float* t1w  = (const float*)d_in[6];
    const float* t1b  = (const float*)d_in[7];
    const float* t2w  = (const float*)d_in[8];
    const float* t2b  = (const float*)d_in[9];
    const float* p1w  = (const float*)d_in[10];
    const float* p1b  = (const float*)d_in[11];
    const float* p2w  = (const float*)d_in[12];
    const float* p2b  = (const float*)d_in[13];
    const float* g1w  = (const float*)d_in[14];
    const float* g1b  = (const float*)d_in[15];
    const float* g2w  = (const float*)d_in[16];
    const float* g2b  = (const float*)d_in[17];
    const float* ww   = (const float*)d_in[18];
    const float* wb   = (const float*)d_in[19];
    const float* vw   = (const float*)d_in[20];
    const float* vb   = (const float*)d_in[21];
    const float* pe1w = (const float*)d_in[22];
    const float* pe2w = (const float*)d_in[23];

    __half* z2   = (__half*)d_ws;
    float* stats = (float*)((char*)d_ws + Z2F * sizeof(__half));

    hipMemsetAsync(stats, 0, 1240 * sizeof(float), stream);

    dim3 grid(WW / 16, HH / 16, BN);
    dim3 blk(256);

    blockNL_k_stage1<<<grid, blk, 0, stream>>>(z, nz_w, nz_b, t1w, t1b, t2w, t2b,
                                               g1w, g1b, g2w, g2b, z2, stats);
    blockNL_k_out<<<grid, blk, 0, stream>>>(x, z, nx_b, p1w, p1b, p2w, p2b,
                                            ww, wb, vw, vb, pe1w, pe2w,
                                            z2, stats, (float*)d_out);
}